// Round 1
// 172.740 us; speedup vs baseline: 1.0670x; 1.0670x over previous
//
#include <hip/hip_runtime.h>

// SSIM, 64 slices of 512x512, 11x11 uniform window (separable box), zero pad.
// R4 redesign: wave-autonomous bands — zero LDS slab, zero main-loop barriers.
// Each wave owns one 16-output-row x 512-col band of one slice:
//  - 8 cols/lane x 64 lanes = full row width per wave
//  - vertical running box sums in registers (5 quantities x 8 cols)
//  - "row leaving the window" values re-loaded from global (L2/L3-hot;
//    entire input = 134 MB < 256 MB Infinity Cache)
//  - horizontal 11-tap from register column sums; the +-5 col halo comes
//    from neighbor lanes via ds_bpermute (10 per quantity), lane 0/63
//    halo forced to zero = image zero-pad
//  - row loads software-pipelined through A/B register banks; all guards
//    are wave-uniform scalar branches.

constexpr int IMG   = 512;
constexpr int RB    = 16;                 // output rows per wave (band)
constexpr int BANDS = IMG / RB;           // 32
constexpr int WPB   = 4;                  // waves per block
constexpr int NBLK  = 64 * BANDS / WPB;   // 512 blocks
constexpr float WSCALE = 1.0f / 121.0f;
constexpr float C1F = 1e-4f;              // 0.01^2
constexpr float C2F = 9e-4f;              // 0.03^2

__device__ __forceinline__ float bperm(int addr, float v) {
  return __int_as_float(__builtin_amdgcn_ds_bpermute(addr, __float_as_int(v)));
}

template <bool ATOMIC>
__global__ __launch_bounds__(256, 2) void ssim_main(const float* __restrict__ x,
                                                    const float* __restrict__ y,
                                                    float* __restrict__ out_ws) {
  __shared__ float wsum[WPB];

  const int tid  = threadIdx.x;
  const int lane = tid & 63;
  const int wid  = tid >> 6;

  // XCD clustering: consecutive blockIdx round-robin the 8 XCDs, so give
  // each XCD a contiguous group of 8 slices (bands of one slice share
  // boundary rows + subtract reloads -> L2 locality).
  const int bid  = blockIdx.x;
  const int xcd  = bid & 7;
  const int qq   = bid >> 3;                // 0..63
  const int z    = xcd * 8 + (qq >> 3);     // slice 0..63
  const int band = (qq & 7) * WPB + wid;    // 0..31
  const int o0   = band * RB;               // first output row
  const int gs   = o0 - 5;                  // first streamed input row

  const float* xs = x + (size_t)z * IMG * IMG + lane * 8;
  const float* ys = y + (size_t)z * IMG * IMG + lane * 8;

  const int addrL = ((lane + 63) & 63) << 2;   // bpermute byte addr: lane-1
  const int addrR = ((lane + 1) & 63) << 2;    // lane+1
  const bool l0  = (lane == 0);
  const bool l63 = (lane == 63);

  float sX[8] = {}, sY[8] = {}, sXX[8] = {}, sYY[8] = {}, sXY[8] = {};
  float cxA[8], cyA[8], oxA[8], oyA[8];
  float cxB[8], cyB[8], oxB[8], oyB[8];
  float acc = 0.f;

  auto ldrow8 = [&](const float* p, bool valid, float (&d)[8]) {
    if (valid) {
      const float4 a = *(const float4*)p;
      const float4 b = *(const float4*)(p + 4);
      d[0] = a.x; d[1] = a.y; d[2] = a.z; d[3] = a.w;
      d[4] = b.x; d[5] = b.y; d[6] = b.z; d[7] = b.w;
    } else {
#pragma unroll
      for (int j = 0; j < 8; ++j) d[j] = 0.f;
    }
  };

  // Horizontal 11-tap window sums for one quantity.
  // Output col c = 8*lane + j, window cols [c-5, c+5].
  // v[-5..-1] = left lane's S[3..7]; v[8..12] = right lane's S[0..4].
  auto hwin = [&](const float (&S)[8], float (&B)[8]) {
    float vm5 = bperm(addrL, S[3]);
    float vm4 = bperm(addrL, S[4]);
    float vm3 = bperm(addrL, S[5]);
    float vm2 = bperm(addrL, S[6]);
    float vm1 = bperm(addrL, S[7]);
    float vp8  = bperm(addrR, S[0]);
    float vp9  = bperm(addrR, S[1]);
    float vp10 = bperm(addrR, S[2]);
    float vp11 = bperm(addrR, S[3]);
    float vp12 = bperm(addrR, S[4]);
    vm5  = l0  ? 0.f : vm5;   vm4  = l0  ? 0.f : vm4;
    vm3  = l0  ? 0.f : vm3;   vm2  = l0  ? 0.f : vm2;
    vm1  = l0  ? 0.f : vm1;
    vp8  = l63 ? 0.f : vp8;   vp9  = l63 ? 0.f : vp9;
    vp10 = l63 ? 0.f : vp10;  vp11 = l63 ? 0.f : vp11;
    vp12 = l63 ? 0.f : vp12;
    float s = (((vm5 + vm4) + (vm3 + vm2)) + ((vm1 + S[0]) + (S[1] + S[2]))) +
              ((S[3] + S[4]) + S[5]);
    B[0] = s;
    s += S[6]  - vm5;  B[1] = s;
    s += S[7]  - vm4;  B[2] = s;
    s += vp8   - vm3;  B[3] = s;
    s += vp9   - vm2;  B[4] = s;
    s += vp10  - vm1;  B[5] = s;
    s += vp11  - S[0]; B[6] = s;
    s += vp12  - S[1]; B[7] = s;
  };

  // One streamed row. Prefetches row i+1 (new + old) into the n*/p* bank,
  // consumes the c*/o* bank loaded by the previous step.
  auto step = [&](int i, bool steady,
                  float (&cx)[8], float (&cy)[8], float (&ox)[8], float (&oy)[8],
                  float (&nx)[8], float (&ny)[8], float (&px)[8], float (&py)[8]) {
    const int gr = gs + i;
    const bool nv = ((unsigned)(gr + 1) < (unsigned)IMG) && (i < RB + 9);
    ldrow8(xs + (gr + 1) * IMG, nv, nx);
    ldrow8(ys + (gr + 1) * IMG, nv, ny);

    if (steady) {
      // old row for iteration i+1 is gr-10; rows before gs were never added.
      const int gro = gr - 10;
      const bool ov = (gro >= 0);
      ldrow8(xs + gro * IMG, ov, px);
      ldrow8(ys + gro * IMG, ov, py);
#pragma unroll
      for (int j = 0; j < 8; ++j) {
        sX[j] += cx[j] - ox[j];
        sY[j] += cy[j] - oy[j];
        sXX[j] = fmaf(cx[j], cx[j], fmaf(-ox[j], ox[j], sXX[j]));
        sYY[j] = fmaf(cy[j], cy[j], fmaf(-oy[j], oy[j], sYY[j]));
        sXY[j] = fmaf(cx[j], cy[j], fmaf(-ox[j], oy[j], sXY[j]));
      }
      float bX[8], bY[8], bXX[8], bYY[8], bXY[8];
      hwin(sX, bX); hwin(sY, bY); hwin(sXX, bXX); hwin(sYY, bYY); hwin(sXY, bXY);
#pragma unroll
      for (int j = 0; j < 8; ++j) {
        const float mu_x = bX[j] * WSCALE;
        const float mu_y = bY[j] * WSCALE;
        const float ex2  = bXX[j] * WSCALE;
        const float ey2  = bYY[j] * WSCALE;
        const float exy  = bXY[j] * WSCALE;
        const float mxx = mu_x * mu_x;
        const float myy = mu_y * mu_y;
        const float mxy = mu_x * mu_y;
        const float num = fmaf(2.f, mxy, C1F) * fmaf(2.f, exy - mxy, C2F);
        const float den = (mxx + myy + C1F) * ((ex2 - mxx) + (ey2 - myy) + C2F);
        acc += num * __builtin_amdgcn_rcpf(den);
      }
    } else {
      // warmup: no row has left the window yet (old banks stay zero),
      // no outputs produced.
#pragma unroll
      for (int j = 0; j < 8; ++j) {
        sX[j] += cx[j];
        sY[j] += cy[j];
        sXX[j] = fmaf(cx[j], cx[j], sXX[j]);
        sYY[j] = fmaf(cy[j], cy[j], sYY[j]);
        sXY[j] = fmaf(cx[j], cy[j], sXY[j]);
      }
    }
  };

  // Prologue: load row gs into bank A; zero both old banks.
  ldrow8(xs + gs * IMG, gs >= 0, cxA);
  ldrow8(ys + gs * IMG, gs >= 0, cyA);
#pragma unroll
  for (int j = 0; j < 8; ++j) {
    oxA[j] = 0.f; oyA[j] = 0.f; oxB[j] = 0.f; oyB[j] = 0.f;
  }

#pragma unroll 1
  for (int i = 0; i < 10; i += 2) {
    step(i,     false, cxA, cyA, oxA, oyA, cxB, cyB, oxB, oyB);
    step(i + 1, false, cxB, cyB, oxB, oyB, cxA, cyA, oxA, oyA);
  }
#pragma unroll 1
  for (int i = 10; i < RB + 10; i += 2) {
    step(i,     true, cxA, cyA, oxA, oyA, cxB, cyB, oxB, oyB);
    step(i + 1, true, cxB, cyB, oxB, oyB, cxA, cyA, oxA, oyA);
  }

  // ---- reduction: wave -> block -> global ----
#pragma unroll
  for (int off = 32; off > 0; off >>= 1) acc += __shfl_down(acc, off, 64);
  if (lane == 0) wsum[wid] = acc;
  __syncthreads();
  if (tid == 0) {
    const float t = wsum[0] + wsum[1] + wsum[2] + wsum[3];
    if (ATOMIC) {
      atomicAdd(out_ws, t);
    } else {
      out_ws[bid] = t;
    }
  }
}

__global__ void ssim_finalize(const float* __restrict__ partials, int n,
                              float* __restrict__ out) {
  __shared__ float wsum[4];
  float acc = 0.f;
  for (int i = threadIdx.x; i < n; i += 256) acc += partials[i];
#pragma unroll
  for (int off = 32; off > 0; off >>= 1) acc += __shfl_down(acc, off, 64);
  if ((threadIdx.x & 63) == 0) wsum[threadIdx.x >> 6] = acc;
  __syncthreads();
  if (threadIdx.x == 0) {
    const float t = wsum[0] + wsum[1] + wsum[2] + wsum[3];
    out[0] = 1.0f - t * (1.0f / (64.0f * 512.0f * 512.0f));
  }
}

__global__ void ssim_zero(float* p) {
  if (threadIdx.x == 0) p[0] = 0.f;
}

__global__ void ssim_finalize_atomic(const float* __restrict__ accp,
                                     float* __restrict__ out) {
  if (threadIdx.x == 0)
    out[0] = 1.0f - accp[0] * (1.0f / (64.0f * 512.0f * 512.0f));
}

extern "C" void kernel_launch(void* const* d_in, const int* in_sizes, int n_in,
                              void* d_out, int out_size, void* d_ws, size_t ws_size,
                              hipStream_t stream) {
  const float* x = (const float*)d_in[0];
  const float* y = (const float*)d_in[1];
  // d_in[2]: uniform 1/121 window, folded into WSCALE.
  float* out = (float*)d_out;

  dim3 grid(NBLK);      // 512 blocks x 256 threads = 2048 waves = 64x32 bands
  dim3 block(256);

  if (ws_size >= (size_t)NBLK * sizeof(float)) {
    float* partials = (float*)d_ws;
    ssim_main<false><<<grid, block, 0, stream>>>(x, y, partials);
    ssim_finalize<<<1, 256, 0, stream>>>(partials, NBLK, out);
  } else {
    float* accp = (float*)d_ws;
    ssim_zero<<<1, 64, 0, stream>>>(accp);
    ssim_main<true><<<grid, block, 0, stream>>>(x, y, accp);
    ssim_finalize_atomic<<<1, 64, 0, stream>>>(accp, out);
  }
}